// Round 5
// baseline (1664.888 us; speedup 1.0000x reference)
//
#include <hip/hip_runtime.h>

// LiftSplatShot voxel pooling: segment-sum of per-point features into a
// (B=2, C=64, 512, 512) fp32 grid.
//
//   points: (B,N,D,H,W,3) f32; x: (B,N,D,H,W,64) f32
//   kept: 0<=px<512, 0<=py<512, pz==0 ; out[b][c][px][py] += x[i][c]
//
// NUMERICS history (absmax vs checker's ref):
//   r1 IEEE-f32 add+div           -> 3.001465   (== r2 bit-identical)
//   r2 f64-div rounded to f32     -> 3.001465   (proves our divide is IEEE RN)
//   r3 f64, f32-image constants   -> 3.046875   (== r4 bit-identical)
//   r4 f64, python constants      -> 3.046875
// Flip statistics: each variant is only ~1-6 misplaced points from ref, but
// f32- and f64-binning are ~20 flips apart -> ref is f32-grade with a ~1e-8
// perturbation vs IEEE divide. That is XLA's jit-time rewrite of
// divide-by-constant into multiply-by-reciprocal: RN32(1/0.2f) == 5.0f
// exactly, off 1.49e-8 from true 1/0.2f. So match the jitted JAX reference:
//   q = RN32( RN32(f + 51.2f) * 5.0f )   (x/y);  z: * 0.125f (exact, == /8)
// Outer op is a multiply feeding a trunc -> no FMA contraction hazard.

#define NX0 512
#define NX1 512
#define CDIM 64

__global__ __launch_bounds__(256) void lss_scatter_kernel(
    const float* __restrict__ points, const float* __restrict__ x,
    float* __restrict__ out, int npoints, int per_batch)
{
    long long gid = (long long)blockIdx.x * blockDim.x + threadIdx.x;
    int wave = (int)(gid >> 6);   // one 64-lane wave per point
    int lane = (int)(gid & 63);   // lane == channel
    if (wave >= npoints) return;

    float fx = points[(size_t)wave * 3 + 0];
    float fy = points[(size_t)wave * 3 + 1];
    float fz = points[(size_t)wave * 3 + 2];

    // XLA-jit semantics: f32 add, then f32 multiply by folded reciprocal.
    float qx = (fx + 51.2f) * 5.0f;    // RN32 add, RN32 mul (recip(0.2f)==5.0f)
    float qy = (fy + 51.2f) * 5.0f;
    float qz = (fz + 5.0f) * 0.125f;   // exact scale, == divide by 8

    int px = (int)qx;                  // trunc toward zero, matches jnp.trunc
    int py = (int)qy;
    int pz = (int)qz;

    if (px < 0 || px >= NX0 || py < 0 || py >= NX1 || pz != 0) return;

    int b = (wave >= per_batch) ? 1 : 0;
    float v = x[(size_t)wave * CDIM + lane];   // coalesced 256B per wave

    // out index: ((b*64 + c) * 512 + px) * 512 + py
    size_t oidx = (((size_t)(b * CDIM + lane)) << 18) + ((size_t)px << 9) + (size_t)py;
    atomicAdd(out + oidx, v);
}

extern "C" void kernel_launch(void* const* d_in, const int* in_sizes, int n_in,
                              void* d_out, int out_size, void* d_ws, size_t ws_size,
                              hipStream_t stream) {
    const float* points = (const float*)d_in[0];
    const float* x      = (const float*)d_in[1];
    float* out = (float*)d_out;

    int npoints   = in_sizes[0] / 3;   // B*N*D*H*W = 826560
    int per_batch = npoints / 2;       // B = 2

    hipMemsetAsync(d_out, 0, (size_t)out_size * sizeof(float), stream);

    long long total_threads = (long long)npoints * 64;
    int threads = 256;
    int blocks = (int)((total_threads + threads - 1) / threads);
    lss_scatter_kernel<<<blocks, threads, 0, stream>>>(points, x, out, npoints, per_batch);
}

// Round 6
// 243.449 us; speedup vs baseline: 6.8388x; 6.8388x over previous
//
#include <hip/hip_runtime.h>

// LiftSplatShot voxel pooling: segment-sum of per-point features into a
// (B=2, C=64, 512, 512) fp32 grid.
//
// NUMERICS (FROZEN — r5 passed, absmax 2e-3): jitted-XLA semantics
//   q = RN32( RN32(f + 51.2f) * 5.0f )  (x/y; recip(0.2f) folds to exactly 5.0f)
//   qz = RN32( RN32(f + 5.0f) * 0.125f ); trunc toward zero; kept: px,py in
//   [0,512), pz==0.
//
// PERF (r5 post-mortem): direct atomics into (b,c,px,py) put a wave's 64
// channel-atomics on 64 cache lines 1MB apart -> 34.8M line-granular RMW
// transactions, WRITE_SIZE 1.09GB for a 128MB output, 1643us. Fix: stage
// into channel-fastest ws[b][px][py][c] so the wave's 64 atomics hit ONE
// contiguous 256B block (4 lines, 16x fewer transactions), then tiled-LDS
// transpose ws(b,s,c) -> out(b,c,s) at streaming BW.

#define NX0 512
#define NX1 512
#define CDIM 64
#define SPATIAL (512 * 512)

__device__ __forceinline__ bool voxel_of(float fx, float fy, float fz,
                                         int& px, int& py) {
    float qx = (fx + 51.2f) * 5.0f;    // XLA: add, mul by folded reciprocal
    float qy = (fy + 51.2f) * 5.0f;
    float qz = (fz + 5.0f) * 0.125f;
    px = (int)qx; py = (int)qy;
    int pz = (int)qz;
    return (px >= 0 && px < NX0 && py >= 0 && py < NX1 && pz == 0);
}

// --- staged path: atomics into ws[b][s][c] (c fastest) ---
__global__ __launch_bounds__(256) void lss_scatter_ws(
    const float* __restrict__ points, const float* __restrict__ x,
    float* __restrict__ ws, int npoints, int per_batch)
{
    long long gid = (long long)blockIdx.x * blockDim.x + threadIdx.x;
    int wave = (int)(gid >> 6);
    int lane = (int)(gid & 63);   // lane == channel
    if (wave >= npoints) return;

    float fx = points[(size_t)wave * 3 + 0];
    float fy = points[(size_t)wave * 3 + 1];
    float fz = points[(size_t)wave * 3 + 2];
    int px, py;
    if (!voxel_of(fx, fy, fz, px, py)) return;

    int b = (wave >= per_batch) ? 1 : 0;
    float v = x[(size_t)wave * CDIM + lane];          // coalesced 256B/wave

    // ws idx: ((b*SPATIAL + px*512 + py) * 64 + c)  -> wave hits 256B block
    size_t widx = ((((size_t)b << 18) + ((size_t)px << 9) + (size_t)py) << 6) + lane;
    atomicAdd(ws + widx, v);
}

// --- transpose ws(b, s, c) -> out(b, c, s), 64x64 tiles via LDS ---
__global__ __launch_bounds__(256) void lss_transpose(
    const float* __restrict__ ws, float* __restrict__ out)
{
    __shared__ float tile[64][65];                    // +1 pad: conflict-free
    int blk = blockIdx.x;                             // 0..8191
    int b  = blk >> 12;                               // 4096 tiles per batch
    int s0 = (blk & 4095) << 6;
    int t = threadIdx.x;

    const float* src = ws + (((size_t)b << 18) + (size_t)s0) * CDIM;
    #pragma unroll
    for (int i = 0; i < 16; ++i) {                    // 4KB fully contiguous/iter
        int idx = i * 256 + t;
        tile[idx >> 6][idx & 63] = src[idx];
    }
    __syncthreads();

    float* dst = out + ((size_t)b * CDIM) * SPATIAL + (size_t)s0;
    #pragma unroll
    for (int i = 0; i < 16; ++i) {                    // 4x 256B segments/iter
        int idx = i * 256 + t;
        int c = idx >> 6, sr = idx & 63;
        dst[(size_t)c * SPATIAL + (size_t)sr] = tile[sr][c];
    }
}

// --- fallback path (r5 kernel): direct atomics into out(b,c,s) ---
__global__ __launch_bounds__(256) void lss_scatter_direct(
    const float* __restrict__ points, const float* __restrict__ x,
    float* __restrict__ out, int npoints, int per_batch)
{
    long long gid = (long long)blockIdx.x * blockDim.x + threadIdx.x;
    int wave = (int)(gid >> 6);
    int lane = (int)(gid & 63);
    if (wave >= npoints) return;

    float fx = points[(size_t)wave * 3 + 0];
    float fy = points[(size_t)wave * 3 + 1];
    float fz = points[(size_t)wave * 3 + 2];
    int px, py;
    if (!voxel_of(fx, fy, fz, px, py)) return;

    int b = (wave >= per_batch) ? 1 : 0;
    float v = x[(size_t)wave * CDIM + lane];
    size_t oidx = (((size_t)(b * CDIM + lane)) << 18) + ((size_t)px << 9) + (size_t)py;
    atomicAdd(out + oidx, v);
}

extern "C" void kernel_launch(void* const* d_in, const int* in_sizes, int n_in,
                              void* d_out, int out_size, void* d_ws, size_t ws_size,
                              hipStream_t stream) {
    const float* points = (const float*)d_in[0];
    const float* x      = (const float*)d_in[1];
    float* out = (float*)d_out;

    int npoints   = in_sizes[0] / 3;   // B*N*D*H*W = 826560
    int per_batch = npoints / 2;       // B = 2

    const size_t WS_NEED = (size_t)2 * SPATIAL * CDIM * sizeof(float);  // 134MB

    long long total_threads = (long long)npoints * 64;
    int threads = 256;
    int blocks = (int)((total_threads + threads - 1) / threads);

    if (ws_size >= WS_NEED) {
        float* ws = (float*)d_ws;
        hipMemsetAsync(ws, 0, WS_NEED, stream);
        lss_scatter_ws<<<blocks, threads, 0, stream>>>(points, x, ws, npoints, per_batch);
        lss_transpose<<<2 * (SPATIAL / 64), 256, 0, stream>>>(ws, out);
        // out fully overwritten by transpose -> no out memset needed
    } else {
        hipMemsetAsync(d_out, 0, (size_t)out_size * sizeof(float), stream);
        lss_scatter_direct<<<blocks, threads, 0, stream>>>(points, x, out, npoints, per_batch);
    }
}